// Round 4
// baseline (425.057 us; speedup 1.0000x reference)
//
#include <hip/hip_runtime.h>
#include <hip/hip_fp16.h>
#include <math.h>

#define BB 2
#define CC 64
#define NN 16384
#define DD 3
#define KK 128
#define EE 262144
#define GG 3
#define PP 64            // n-chunks for spectral-forward partials
#define LL (NN/PP)       // 256 n per chunk

// ---- workspace layout (float elements) ----
constexpr size_t OFF_XT   = 0;                                  // xT[b][n][i]
constexpr size_t OFF_PC   = OFF_XT   + (size_t)BB*NN*CC;        // partial A_c
constexpr size_t OFF_PS   = OFF_PC   + (size_t)BB*PP*CC*KK;     // partial A_s
// bin4 aliases pc/ps (pc/ps dead after k_ared; k_fill runs later in-stream)
constexpr size_t OFF_BIN4 = OFF_PC;                             // float4 binlist[b][E]
constexpr size_t OFF_AC   = OFF_PS   + (size_t)BB*PP*CC*KK;     // A_c[b][i][k]
constexpr size_t OFF_AS   = OFF_AC   + (size_t)BB*CC*KK;
constexpr size_t OFF_FTC  = OFF_AS   + (size_t)BB*CC*KK;        // 2*f_c[b][k][o]
constexpr size_t OFF_FTS  = OFF_FTC  + (size_t)BB*KK*CC;        // 2*f_s[b][k][o]
constexpr size_t OFF_F0   = OFF_FTS  + (size_t)BB*KK*CC;        // f0[b][o]
constexpr size_t OFF_X0   = OFF_F0   + (size_t)BB*CC;           // x0[b][i]
constexpr size_t OFF_CNT  = OFF_X0   + (size_t)BB*CC;           // int counts (zeroed)
constexpr size_t OFF_OFFS = OFF_CNT  + (size_t)BB*NN;           // int offsets
constexpr size_t OFF_CUR  = OFF_OFFS + (size_t)BB*NN;           // int cursor
constexpr size_t OFF_GRT  = OFF_CUR  + (size_t)BB*NN;           // gradfT[b][g][n]
constexpr size_t OFF_H    = OFF_GRT  + (size_t)BB*192*NN;       // h[b][i][n]
constexpr size_t OFF_WT   = OFF_H    + (size_t)BB*CC*NN;        // W^T  [j][o]
constexpr size_t OFF_WXT  = OFF_WT   + (size_t)CC*CC;           // wx^T [j][i]
constexpr size_t OFF_W2T  = OFF_WXT  + (size_t)CC*CC;           // w2^T [i][o]
constexpr size_t OFF_GWT  = OFF_W2T  + (size_t)CC*CC;           // gw^T [g][o]
constexpr size_t OFF_GWXT = OFF_GWT  + (size_t)CC*CC*DD;        // geo_wx^T [g][i]

// ---- small transposes ----
__global__ void k_prep(const float* __restrict__ W, const float* __restrict__ gw,
                       const float* __restrict__ geo_wx, const float* __restrict__ wx,
                       const float* __restrict__ w2,
                       float* WT, float* wxT, float* w2T, float* gwT, float* gwxT) {
    int idx = blockIdx.x*256 + threadIdx.x;
    if (idx < CC*CC) { int j = idx>>6, o = idx&63; WT[idx]  = W[o*CC+j];  }
    if (idx < CC*CC) { int j = idx>>6, i = idx&63; wxT[idx] = wx[i*CC+j]; }
    if (idx < CC*CC) { int i = idx>>6, o = idx&63; w2T[idx] = w2[o*CC+i]; }
    if (idx < CC*CC*DD) { int g = idx>>6, o = idx&63; gwT[idx] = gw[o*(CC*DD)+g]; }
    if (idx < GG*CC) { int g = idx>>6, i = idx&63; gwxT[idx] = geo_wx[i*GG+g]; }
}

// ---- transpose x -> xT[b][n][i] ----
__global__ void __launch_bounds__(256) k_xt(const float* __restrict__ x,
                                            float* __restrict__ xT) {
    int blk = blockIdx.x;
    int b = blk / (NN/64);
    int n0 = (blk % (NN/64)) * 64;
    __shared__ float tile[64][65];
    int tid = threadIdx.x;
    int c = tid & 63, r4 = tid >> 6;
    for (int rr = 0; rr < 16; rr++) {
        int i = r4*16 + rr;
        tile[i][c] = x[((size_t)b*CC + i)*NN + n0 + c];
    }
    __syncthreads();
    for (int rr = 0; rr < 16; rr++) {
        int nn = r4*16 + rr;
        xT[((size_t)b*NN + n0 + nn)*CC + c] = tile[c][nn];
    }
}

// ---- x0[b][i] = sum_n x[b,i,n] * nw[b,n] ----
__global__ void __launch_bounds__(256) k_x0(const float* __restrict__ x,
                                            const float* __restrict__ nwt,
                                            float* __restrict__ x0) {
    int b = blockIdx.x >> 6;
    int i = blockIdx.x & 63;
    int tid = threadIdx.x;
    const float4* __restrict__ xr = (const float4*)&x[((size_t)b*CC + i)*NN];
    const float4* __restrict__ wr = (const float4*)&nwt[(size_t)b*NN];
    float s = 0.f;
    for (int t = tid; t < NN/4; t += 256) {
        float4 xv = xr[t];
        float4 wv = wr[t];
        s += xv.x*wv.x + xv.y*wv.y + xv.z*wv.z + xv.w*wv.w;
    }
    __shared__ float red[256];
    red[tid] = s;
    __syncthreads();
    for (int off = 128; off > 0; off >>= 1) {
        if (tid < off) red[tid] += red[tid+off];
        __syncthreads();
    }
    if (tid == 0) x0[b*CC + i] = red[0];
}

// ---- spectral forward partials: A_c/A_s[b][i][k] over n-chunks ----
__global__ void __launch_bounds__(256) k_a(const float* __restrict__ xT,
                                           const float* __restrict__ nodes,
                                           const float* __restrict__ nwt,
                                           const float* __restrict__ modes,
                                           float* __restrict__ pc, float* __restrict__ ps) {
    int bc = blockIdx.x;
    int b = bc / PP, chunk = bc % PP;
    int tid = threadIdx.x;
    int lane = tid & 63;
    int w = tid >> 6;
    int khalf = w & 1;
    int ig = blockIdx.y*2 + (w >> 1);
    int k = khalf*64 + lane;
    int i0 = __builtin_amdgcn_readfirstlane(ig * 16);
    float m0 = modes[k*3+0], m1 = modes[k*3+1], m2 = modes[k*3+2];
    float ac[16], as[16];
#pragma unroll
    for (int j = 0; j < 16; j++) { ac[j]=0.f; as[j]=0.f; }
    int nbase = chunk*LL;
    for (int t = 0; t < LL; t++) {
        int n = nbase + t;
        float nd0 = nodes[(b*NN+n)*3+0], nd1 = nodes[(b*NN+n)*3+1], nd2 = nodes[(b*NN+n)*3+2];
        float nw = nwt[b*NN+n];
        float tt = nd0*m0 + nd1*m1 + nd2*m2;
        float cv = __cosf(tt) * nw, sv = __sinf(tt) * nw;
        const float* __restrict__ xrow = &xT[((size_t)b*NN+n)*CC + i0];
#pragma unroll
        for (int j = 0; j < 16; j++) {
            float xv = xrow[j];
            ac[j] = fmaf(xv, cv, ac[j]);
            as[j] = fmaf(xv, sv, as[j]);
        }
    }
    int base = (b*PP + chunk)*CC;
#pragma unroll
    for (int j = 0; j < 16; j++) {
        pc[(size_t)(base + i0 + j)*KK + k] = ac[j];
        ps[(size_t)(base + i0 + j)*KK + k] = as[j];
    }
}

__global__ void k_ared(const float* __restrict__ pc, const float* __restrict__ ps,
                       float* __restrict__ Ac, float* __restrict__ As) {
    int idx = blockIdx.x*256 + threadIdx.x;
    if (idx >= BB*CC*KK) return;
    int b = idx / (CC*KK);
    int r = idx % (CC*KK);
    float sc = 0.f, ss = 0.f;
    for (int ch = 0; ch < PP; ch++) {
        size_t o = ((size_t)(b*PP + ch)*CC)*KK + r;
        sc += pc[o]; ss += ps[o];
    }
    Ac[idx] = sc; As[idx] = ss;
}

// ---- channel mix -> 2*f_c, 2*f_s in [b][k][o] layout, + f0 ----
__global__ void k_b(const float* __restrict__ Ac, const float* __restrict__ As,
                    const float* __restrict__ wc, const float* __restrict__ wsw,
                    const float* __restrict__ w0, const float* __restrict__ x0,
                    float* __restrict__ fTc, float* __restrict__ fTs, float* __restrict__ f0) {
    int b = blockIdx.x / CC, o = blockIdx.x % CC;
    int k = threadIdx.x;
    float fc = 0.f, fs = 0.f;
    for (int i = 0; i < CC; i++) {
        float a_c = Ac[(b*CC+i)*KK + k];
        float a_s = As[(b*CC+i)*KK + k];
        float wcc = wc[((size_t)(i*CC+o))*KK + k];
        float wss = wsw[((size_t)(i*CC+o))*KK + k];
        fc += a_c*wcc + a_s*wss;
        fs += a_c*wss - a_s*wcc;
    }
    fTc[(b*KK+k)*CC + o] = 2.f*fc;
    fTs[(b*KK+k)*CC + o] = 2.f*fs;
    if (threadIdx.x == 0) {
        float acc = 0.f;
        for (int i = 0; i < CC; i++) acc += x0[b*CC+i]*w0[i*CC+o];
        f0[b*CC+o] = acc;
    }
}

// ---- edge binning ----
__global__ void k_count(const int* __restrict__ edges, int* __restrict__ counts) {
    int idx = blockIdx.x*256 + threadIdx.x;
    if (idx >= BB*EE) return;
    int tgt = edges[(size_t)idx*2 + 0];
    int b = idx / EE;
    atomicAdd(&counts[b*NN + tgt], 1);
}

__global__ void __launch_bounds__(1024) k_scan(const int* __restrict__ counts,
                                               int* __restrict__ offsets, int* __restrict__ cursor) {
    __shared__ int part[1024];
    int b = blockIdx.x;
    int tid = threadIdx.x;
    int base = tid*16;
    int loc[16]; int s = 0;
    for (int j = 0; j < 16; j++) { loc[j] = counts[b*NN + base + j]; s += loc[j]; }
    part[tid] = s;
    __syncthreads();
    for (int off = 1; off < 1024; off <<= 1) {
        int v = (tid >= off) ? part[tid-off] : 0;
        __syncthreads();
        part[tid] += v;
        __syncthreads();
    }
    int excl = part[tid] - s;
    for (int j = 0; j < 16; j++) {
        offsets[b*NN+base+j] = excl;
        cursor[b*NN+base+j]  = excl;
        excl += loc[j];
    }
}

// ---- fill bins with packed {src, w0, w1, w2} entries ----
__global__ void k_fill(const int* __restrict__ edges, const float* __restrict__ egw,
                       int* __restrict__ cursor, float4* __restrict__ bin4) {
    int idx = blockIdx.x*256 + threadIdx.x;
    if (idx >= BB*EE) return;
    int b = idx / EE;
    int tgt = edges[(size_t)idx*2+0];
    int src = edges[(size_t)idx*2+1];
    const float* __restrict__ ew = &egw[(size_t)idx*3];
    float w0 = ew[0], w1 = ew[1], w2 = ew[2];
    int pos = atomicAdd(&cursor[b*NN+tgt], 1);
    bin4[(size_t)b*EE + pos] = make_float4(__int_as_float(src), w0, w1, w2);
}

// ---- per-node edge accumulate -> gradfT[b][g][n] ----
#define ECAP 1024
__global__ void __launch_bounds__(256) k_edge(const float* __restrict__ xT,
                                              const int* __restrict__ offsets,
                                              const float4* __restrict__ bin4,
                                              float* __restrict__ gradfT) {
    int blk = blockIdx.x;
    int b = blk / (NN/16);
    int n0 = (blk % (NN/16)) * 16;
    int tid = threadIdx.x;
    int lane = tid & 63;
    int w = tid >> 6;                 // 4 waves, 4 nodes each
    __shared__ float4 ebuf[ECAP];
    __shared__ float gl[16][193];
    __shared__ int soff[17];
    if (tid < 16) soff[tid] = offsets[b*NN + n0 + tid];
    if (tid == 16) soff[16] = (n0 + 16 < NN) ? offsets[b*NN + n0 + 16] : EE;
    __syncthreads();
    int base = soff[0];
    int end  = soff[16];
    const float* __restrict__ xTb = &xT[(size_t)b*NN*CC + lane];

    float a0[4], a1[4], a2[4], s0[4], s1[4], s2[4];
#pragma unroll
    for (int q = 0; q < 4; q++) { a0[q]=a1[q]=a2[q]=0.f; s0[q]=s1[q]=s2[q]=0.f; }

    for (int cs = base; cs < end; cs += ECAP) {
        int ce = min(cs + ECAP, end);
        __syncthreads();
        for (int t = cs + tid; t < ce; t += 256)
            ebuf[t - cs] = bin4[(size_t)b*EE + t];
        __syncthreads();
#pragma unroll
        for (int q = 0; q < 4; q++) {
            int nl = w*4 + q;
            int js = max(soff[nl], cs);
            int je = min(soff[nl+1], ce);
#pragma unroll 2
            for (int j = js; j < je; j++) {
                float4 e = ebuf[j - cs];
                int src = __float_as_int(e.x);
                float xs = xTb[(size_t)src*CC];
                a0[q] = fmaf(xs, e.y, a0[q]);
                a1[q] = fmaf(xs, e.z, a1[q]);
                a2[q] = fmaf(xs, e.w, a2[q]);
                s0[q] += e.y; s1[q] += e.z; s2[q] += e.w;
            }
        }
    }
    __syncthreads();
#pragma unroll
    for (int q = 0; q < 4; q++) {
        int nl = w*4 + q;
        float xtgt = xTb[(size_t)(n0 + nl)*CC];
        gl[nl][lane*3+0] = a0[q] - xtgt*s0[q];
        gl[nl][lane*3+1] = a1[q] - xtgt*s1[q];
        gl[nl][lane*3+2] = a2[q] - xtgt*s2[q];
    }
    __syncthreads();
    for (int t = tid; t < 16*192; t += 256) {
        int g = t >> 4, nl = t & 15;
        gradfT[((size_t)b*192+g)*NN + n0 + nl] = gl[nl][g];
    }
}

// ---- h[b][i][n] = softsign(geo_wx@geo) * (wx@x) : 256-thread blocks ----
__global__ void __launch_bounds__(256) k_h(const float* __restrict__ x,
                                           const float* __restrict__ geo,
                                           const float* __restrict__ wxT,
                                           const float* __restrict__ gwxT,
                                           float* __restrict__ hbuf) {
    int blk = blockIdx.x;
    int b = blk / (NN/256);
    int n0 = (blk % (NN/256)) * 256;
    int i0 = blockIdx.y * 32;
    int n = n0 + threadIdx.x;
    float xw[32];
#pragma unroll
    for (int ii = 0; ii < 32; ii++) xw[ii] = 0.f;
    for (int j = 0; j < CC; j++) {
        float xv = x[((size_t)b*CC+j)*NN + n];
        const float* __restrict__ wr = &wxT[j*CC + i0];
#pragma unroll
        for (int ii = 0; ii < 32; ii++) xw[ii] = fmaf(wr[ii], xv, xw[ii]);
    }
    float g0 = geo[((size_t)b*GG+0)*NN + n];
    float g1 = geo[((size_t)b*GG+1)*NN + n];
    float g2 = geo[((size_t)b*GG+2)*NN + n];
#pragma unroll
    for (int ii = 0; ii < 32; ii++) {
        int i = i0 + ii;
        float t = gwxT[0*CC+i]*g0 + gwxT[1*CC+i]*g1 + gwxT[2*CC+i]*g2;
        float ssv = t / (1.f + fabsf(t));
        hbuf[((size_t)b*CC+i)*NN + n] = ssv * xw[ii];
    }
}

// ---- fused final: x1 + x2 + x3 + x4 -> exact GELU ----
// cos/sin packed as __half2 in LDS: 32 KB/block -> ~5 blocks/CU occupancy
__global__ void __launch_bounds__(256) k_c(const float* __restrict__ x,
                                           const float* __restrict__ nodes,
                                           const float* __restrict__ modes,
                                           const float* __restrict__ fTc,
                                           const float* __restrict__ fTs,
                                           const float* __restrict__ f0,
                                           const float* __restrict__ WT,
                                           const float* __restrict__ w2T,
                                           const float* __restrict__ gwT,
                                           const float* __restrict__ gradfT,
                                           const float* __restrict__ hbuf,
                                           float* __restrict__ out) {
    int blk = blockIdx.x;
    int b = blk / (NN/64);
    int n0 = (blk % (NN/64)) * 64;
    int tid = threadIdx.x;
    int lane = tid & 63;
    int o0 = __builtin_amdgcn_readfirstlane((tid >> 6) * 16);
    int n = n0 + lane;
    __shared__ __half2 cs[KK*64];    // packed {cos, sin}, 32 KB
    float nd0 = nodes[((size_t)b*NN+n)*3+0];
    float nd1 = nodes[((size_t)b*NN+n)*3+1];
    float nd2 = nodes[((size_t)b*NN+n)*3+2];
    for (int r = 0; r < 32; r++) {
        int k = __builtin_amdgcn_readfirstlane(r*4 + (tid >> 6));
        float t = nd0*modes[k*3+0] + nd1*modes[k*3+1] + nd2*modes[k*3+2];
        cs[k*64+lane] = __floats2half2_rn(__cosf(t), __sinf(t));
    }
    __syncthreads();
    float acc[16];
    const float* __restrict__ f0p = &f0[b*CC + o0];
#pragma unroll
    for (int oo = 0; oo < 16; oo++) acc[oo] = f0p[oo];
    for (int k = 0; k < KK; k++) {
        __half2 h = cs[k*64 + lane];
        float cv = __low2float(h);
        float sv = __high2float(h);
        const float* __restrict__ fc = &fTc[(b*KK+k)*CC + o0];
        const float* __restrict__ fs = &fTs[(b*KK+k)*CC + o0];
#pragma unroll
        for (int oo = 0; oo < 16; oo++)
            acc[oo] += fc[oo]*cv - fs[oo]*sv;
    }
    for (int j = 0; j < CC; j++) {
        float xv = x[((size_t)b*CC+j)*NN + n];
        const float* __restrict__ wr = &WT[j*CC + o0];
#pragma unroll
        for (int oo = 0; oo < 16; oo++) acc[oo] = fmaf(wr[oo], xv, acc[oo]);
    }
    for (int i = 0; i < CC; i++) {
        float hv = hbuf[((size_t)b*CC+i)*NN + n];
        const float* __restrict__ wr = &w2T[i*CC + o0];
#pragma unroll
        for (int oo = 0; oo < 16; oo++) acc[oo] = fmaf(wr[oo], hv, acc[oo]);
    }
    for (int g = 0; g < 192; g++) {
        float gv = gradfT[((size_t)b*192+g)*NN + n];
        const float* __restrict__ wr = &gwT[g*CC + o0];
#pragma unroll
        for (int oo = 0; oo < 16; oo++) acc[oo] = fmaf(wr[oo], gv, acc[oo]);
    }
#pragma unroll
    for (int oo = 0; oo < 16; oo++) {
        float v = acc[oo];
        float r = 0.5f * v * (1.f + erff(v * 0.70710678118654752f));
        out[((size_t)b*CC + o0 + oo)*NN + n] = r;
    }
}

extern "C" void kernel_launch(void* const* d_in, const int* in_sizes, int n_in,
                              void* d_out, int out_size, void* d_ws, size_t ws_size,
                              hipStream_t stream) {
    const float* x      = (const float*)d_in[0];
    const float* nodes  = (const float*)d_in[1];
    const float* nwt    = (const float*)d_in[2];
    const float* geo    = (const float*)d_in[3];
    const int*   edges  = (const int*)d_in[4];
    const float* egw    = (const float*)d_in[5];
    const float* modes  = (const float*)d_in[6];
    const float* wc     = (const float*)d_in[7];
    const float* wsw    = (const float*)d_in[8];
    const float* w0     = (const float*)d_in[9];
    const float* W      = (const float*)d_in[10];
    const float* gw     = (const float*)d_in[11];
    const float* geo_wx = (const float*)d_in[12];
    const float* wx     = (const float*)d_in[13];
    const float* w2     = (const float*)d_in[14];

    float* ws   = (float*)d_ws;
    float* xT   = ws + OFF_XT;
    float* pc   = ws + OFF_PC;
    float* ps   = ws + OFF_PS;
    float* Ac   = ws + OFF_AC;
    float* As   = ws + OFF_AS;
    float* fTc  = ws + OFF_FTC;
    float* fTs  = ws + OFF_FTS;
    float* f0   = ws + OFF_F0;
    float* x0   = ws + OFF_X0;
    int*  counts = (int*)(ws + OFF_CNT);
    int*  offs   = (int*)(ws + OFF_OFFS);
    int*  cur    = (int*)(ws + OFF_CUR);
    float4* bin4 = (float4*)(ws + OFF_BIN4);
    float* gradfT = ws + OFF_GRT;
    float* hbuf   = ws + OFF_H;
    float* WT   = ws + OFF_WT;
    float* wxT  = ws + OFF_WXT;
    float* w2T  = ws + OFF_W2T;
    float* gwT  = ws + OFF_GWT;
    float* gwxT = ws + OFF_GWXT;
    float* out  = (float*)d_out;

    hipMemsetAsync(counts, 0, (size_t)(BB*NN)*sizeof(int), stream);

    k_prep <<<48, 256, 0, stream>>>(W, gw, geo_wx, wx, w2, WT, wxT, w2T, gwT, gwxT);
    k_xt   <<<BB*(NN/64), 256, 0, stream>>>(x, xT);
    k_x0   <<<BB*CC, 256, 0, stream>>>(x, nwt, x0);
    k_a    <<<dim3(BB*PP, 2), 256, 0, stream>>>(xT, nodes, nwt, modes, pc, ps);
    k_ared <<<(BB*CC*KK)/256, 256, 0, stream>>>(pc, ps, Ac, As);
    k_b    <<<BB*CC, 128, 0, stream>>>(Ac, As, wc, wsw, w0, x0, fTc, fTs, f0);
    k_count<<<(BB*EE)/256, 256, 0, stream>>>(edges, counts);
    k_scan <<<BB, 1024, 0, stream>>>(counts, offs, cur);
    k_fill <<<(BB*EE)/256, 256, 0, stream>>>(edges, egw, cur, bin4);
    k_edge <<<BB*(NN/16), 256, 0, stream>>>(xT, offs, bin4, gradfT);
    k_h    <<<dim3(BB*(NN/256), 2), 256, 0, stream>>>(x, geo, wxT, gwxT, hbuf);
    k_c    <<<BB*(NN/64), 256, 0, stream>>>(x, nodes, modes, fTc, fTs, f0, WT, w2T, gwT,
                                            gradfT, hbuf, out);
}

// Round 5
// 411.157 us; speedup vs baseline: 1.0338x; 1.0338x over previous
//
#include <hip/hip_runtime.h>
#include <hip/hip_fp16.h>
#include <math.h>

#define BB 2
#define CC 64
#define NN 16384
#define DD 3
#define KK 128
#define EE 262144
#define GG 3
#define PP 64            // n-chunks for spectral-forward partials
#define LL (NN/PP)       // 256 n per chunk

// ---- workspace layout (float elements) ----
constexpr size_t OFF_XT   = 0;                                  // xT[b][n][i]
constexpr size_t OFF_PC   = OFF_XT   + (size_t)BB*NN*CC;        // partial A_c
constexpr size_t OFF_PS   = OFF_PC   + (size_t)BB*PP*CC*KK;     // partial A_s
// bin4 aliases pc/ps (pc/ps dead after k_ared; k_fill runs later in-stream)
constexpr size_t OFF_BIN4 = OFF_PC;                             // float4 binlist[b][E]
constexpr size_t OFF_AC   = OFF_PS   + (size_t)BB*PP*CC*KK;     // A_c[b][i][k]
constexpr size_t OFF_AS   = OFF_AC   + (size_t)BB*CC*KK;
constexpr size_t OFF_FTC  = OFF_AS   + (size_t)BB*CC*KK;        // 2*f_c[b][k][o]
constexpr size_t OFF_FTS  = OFF_FTC  + (size_t)BB*KK*CC;        // 2*f_s[b][k][o]
constexpr size_t OFF_F0   = OFF_FTS  + (size_t)BB*KK*CC;        // f0[b][o]
constexpr size_t OFF_X0   = OFF_F0   + (size_t)BB*CC;           // x0[b][i]
constexpr size_t OFF_CNT  = OFF_X0   + (size_t)BB*CC;           // int counts (zeroed)
constexpr size_t OFF_OFFS = OFF_CNT  + (size_t)BB*NN;           // int offsets
constexpr size_t OFF_CUR  = OFF_OFFS + (size_t)BB*NN;           // int cursor
constexpr size_t OFF_GRT  = OFF_CUR  + (size_t)BB*NN;           // gradfT[b][g][n]
constexpr size_t OFF_WT   = OFF_GRT  + (size_t)BB*192*NN;       // W^T  [j][o]
constexpr size_t OFF_WXT  = OFF_WT   + (size_t)CC*CC;           // wx^T [j][i]
constexpr size_t OFF_W2T  = OFF_WXT  + (size_t)CC*CC;           // w2^T [i][o]
constexpr size_t OFF_GWT  = OFF_W2T  + (size_t)CC*CC;           // gw^T [g][o]
constexpr size_t OFF_GWXT = OFF_GWT  + (size_t)CC*CC*DD;        // geo_wx^T [g][i]

// ---- small transposes ----
__global__ void k_prep(const float* __restrict__ W, const float* __restrict__ gw,
                       const float* __restrict__ geo_wx, const float* __restrict__ wx,
                       const float* __restrict__ w2,
                       float* WT, float* wxT, float* w2T, float* gwT, float* gwxT) {
    int idx = blockIdx.x*256 + threadIdx.x;
    if (idx < CC*CC) { int j = idx>>6, o = idx&63; WT[idx]  = W[o*CC+j];  }
    if (idx < CC*CC) { int j = idx>>6, i = idx&63; wxT[idx] = wx[i*CC+j]; }
    if (idx < CC*CC) { int i = idx>>6, o = idx&63; w2T[idx] = w2[o*CC+i]; }
    if (idx < CC*CC*DD) { int g = idx>>6, o = idx&63; gwT[idx] = gw[o*(CC*DD)+g]; }
    if (idx < GG*CC) { int g = idx>>6, i = idx&63; gwxT[idx] = geo_wx[i*GG+g]; }
}

// ---- transpose x -> xT[b][n][i] ----
__global__ void __launch_bounds__(256) k_xt(const float* __restrict__ x,
                                            float* __restrict__ xT) {
    int blk = blockIdx.x;
    int b = blk / (NN/64);
    int n0 = (blk % (NN/64)) * 64;
    __shared__ float tile[64][65];
    int tid = threadIdx.x;
    int c = tid & 63, r4 = tid >> 6;
    for (int rr = 0; rr < 16; rr++) {
        int i = r4*16 + rr;
        tile[i][c] = x[((size_t)b*CC + i)*NN + n0 + c];
    }
    __syncthreads();
    for (int rr = 0; rr < 16; rr++) {
        int nn = r4*16 + rr;
        xT[((size_t)b*NN + n0 + nn)*CC + c] = tile[c][nn];
    }
}

// ---- x0[b][i] = sum_n x[b,i,n] * nw[b,n] ----
__global__ void __launch_bounds__(256) k_x0(const float* __restrict__ x,
                                            const float* __restrict__ nwt,
                                            float* __restrict__ x0) {
    int b = blockIdx.x >> 6;
    int i = blockIdx.x & 63;
    int tid = threadIdx.x;
    const float4* __restrict__ xr = (const float4*)&x[((size_t)b*CC + i)*NN];
    const float4* __restrict__ wr = (const float4*)&nwt[(size_t)b*NN];
    float s = 0.f;
    for (int t = tid; t < NN/4; t += 256) {
        float4 xv = xr[t];
        float4 wv = wr[t];
        s += xv.x*wv.x + xv.y*wv.y + xv.z*wv.z + xv.w*wv.w;
    }
    __shared__ float red[256];
    red[tid] = s;
    __syncthreads();
    for (int off = 128; off > 0; off >>= 1) {
        if (tid < off) red[tid] += red[tid+off];
        __syncthreads();
    }
    if (tid == 0) x0[b*CC + i] = red[0];
}

// ---- spectral forward partials: A_c/A_s[b][i][k] over n-chunks ----
__global__ void __launch_bounds__(256) k_a(const float* __restrict__ xT,
                                           const float* __restrict__ nodes,
                                           const float* __restrict__ nwt,
                                           const float* __restrict__ modes,
                                           float* __restrict__ pc, float* __restrict__ ps) {
    int bc = blockIdx.x;
    int b = bc / PP, chunk = bc % PP;
    int tid = threadIdx.x;
    int lane = tid & 63;
    int w = tid >> 6;
    int khalf = w & 1;
    int ig = blockIdx.y*2 + (w >> 1);
    int k = khalf*64 + lane;
    int i0 = __builtin_amdgcn_readfirstlane(ig * 16);
    float m0 = modes[k*3+0], m1 = modes[k*3+1], m2 = modes[k*3+2];
    float ac[16], as[16];
#pragma unroll
    for (int j = 0; j < 16; j++) { ac[j]=0.f; as[j]=0.f; }
    int nbase = chunk*LL;
    for (int t = 0; t < LL; t++) {
        int n = nbase + t;
        float nd0 = nodes[(b*NN+n)*3+0], nd1 = nodes[(b*NN+n)*3+1], nd2 = nodes[(b*NN+n)*3+2];
        float nw = nwt[b*NN+n];
        float tt = nd0*m0 + nd1*m1 + nd2*m2;
        float cv = __cosf(tt) * nw, sv = __sinf(tt) * nw;
        const float* __restrict__ xrow = &xT[((size_t)b*NN+n)*CC + i0];
#pragma unroll
        for (int j = 0; j < 16; j++) {
            float xv = xrow[j];
            ac[j] = fmaf(xv, cv, ac[j]);
            as[j] = fmaf(xv, sv, as[j]);
        }
    }
    int base = (b*PP + chunk)*CC;
#pragma unroll
    for (int j = 0; j < 16; j++) {
        pc[(size_t)(base + i0 + j)*KK + k] = ac[j];
        ps[(size_t)(base + i0 + j)*KK + k] = as[j];
    }
}

__global__ void k_ared(const float* __restrict__ pc, const float* __restrict__ ps,
                       float* __restrict__ Ac, float* __restrict__ As) {
    int idx = blockIdx.x*256 + threadIdx.x;
    if (idx >= BB*CC*KK) return;
    int b = idx / (CC*KK);
    int r = idx % (CC*KK);
    float sc = 0.f, ss = 0.f;
    for (int ch = 0; ch < PP; ch++) {
        size_t o = ((size_t)(b*PP + ch)*CC)*KK + r;
        sc += pc[o]; ss += ps[o];
    }
    Ac[idx] = sc; As[idx] = ss;
}

// ---- channel mix -> 2*f_c, 2*f_s in [b][k][o] layout, + f0 ----
__global__ void k_b(const float* __restrict__ Ac, const float* __restrict__ As,
                    const float* __restrict__ wc, const float* __restrict__ wsw,
                    const float* __restrict__ w0, const float* __restrict__ x0,
                    float* __restrict__ fTc, float* __restrict__ fTs, float* __restrict__ f0) {
    int b = blockIdx.x / CC, o = blockIdx.x % CC;
    int k = threadIdx.x;
    float fc = 0.f, fs = 0.f;
    for (int i = 0; i < CC; i++) {
        float a_c = Ac[(b*CC+i)*KK + k];
        float a_s = As[(b*CC+i)*KK + k];
        float wcc = wc[((size_t)(i*CC+o))*KK + k];
        float wss = wsw[((size_t)(i*CC+o))*KK + k];
        fc += a_c*wcc + a_s*wss;
        fs += a_c*wss - a_s*wcc;
    }
    fTc[(b*KK+k)*CC + o] = 2.f*fc;
    fTs[(b*KK+k)*CC + o] = 2.f*fs;
    if (threadIdx.x == 0) {
        float acc = 0.f;
        for (int i = 0; i < CC; i++) acc += x0[b*CC+i]*w0[i*CC+o];
        f0[b*CC+o] = acc;
    }
}

// ---- edge binning ----
__global__ void k_count(const int* __restrict__ edges, int* __restrict__ counts) {
    int idx = blockIdx.x*256 + threadIdx.x;
    if (idx >= BB*EE) return;
    int tgt = edges[(size_t)idx*2 + 0];
    int b = idx / EE;
    atomicAdd(&counts[b*NN + tgt], 1);
}

__global__ void __launch_bounds__(1024) k_scan(const int* __restrict__ counts,
                                               int* __restrict__ offsets, int* __restrict__ cursor) {
    __shared__ int part[1024];
    int b = blockIdx.x;
    int tid = threadIdx.x;
    int base = tid*16;
    int loc[16]; int s = 0;
    for (int j = 0; j < 16; j++) { loc[j] = counts[b*NN + base + j]; s += loc[j]; }
    part[tid] = s;
    __syncthreads();
    for (int off = 1; off < 1024; off <<= 1) {
        int v = (tid >= off) ? part[tid-off] : 0;
        __syncthreads();
        part[tid] += v;
        __syncthreads();
    }
    int excl = part[tid] - s;
    for (int j = 0; j < 16; j++) {
        offsets[b*NN+base+j] = excl;
        cursor[b*NN+base+j]  = excl;
        excl += loc[j];
    }
}

// ---- fill bins with packed {src, w0, w1, w2} entries ----
__global__ void k_fill(const int* __restrict__ edges, const float* __restrict__ egw,
                       int* __restrict__ cursor, float4* __restrict__ bin4) {
    int idx = blockIdx.x*256 + threadIdx.x;
    if (idx >= BB*EE) return;
    int b = idx / EE;
    int tgt = edges[(size_t)idx*2+0];
    int src = edges[(size_t)idx*2+1];
    const float* __restrict__ ew = &egw[(size_t)idx*3];
    float w0 = ew[0], w1 = ew[1], w2 = ew[2];
    int pos = atomicAdd(&cursor[b*NN+tgt], 1);
    bin4[(size_t)b*EE + pos] = make_float4(__int_as_float(src), w0, w1, w2);
}

// ---- per-node edge accumulate -> gradfT[b][g][n] ----
#define ECAP 1024
__global__ void __launch_bounds__(256) k_edge(const float* __restrict__ xT,
                                              const int* __restrict__ offsets,
                                              const float4* __restrict__ bin4,
                                              float* __restrict__ gradfT) {
    int blk = blockIdx.x;
    int b = blk / (NN/16);
    int n0 = (blk % (NN/16)) * 16;
    int tid = threadIdx.x;
    int lane = tid & 63;
    int w = tid >> 6;                 // 4 waves, 4 nodes each
    __shared__ float4 ebuf[ECAP];
    __shared__ float gl[16][193];
    __shared__ int soff[17];
    if (tid < 16) soff[tid] = offsets[b*NN + n0 + tid];
    if (tid == 16) soff[16] = (n0 + 16 < NN) ? offsets[b*NN + n0 + 16] : EE;
    __syncthreads();
    int base = soff[0];
    int end  = soff[16];
    const float* __restrict__ xTb = &xT[(size_t)b*NN*CC + lane];

    float a0[4], a1[4], a2[4], s0[4], s1[4], s2[4];
#pragma unroll
    for (int q = 0; q < 4; q++) { a0[q]=a1[q]=a2[q]=0.f; s0[q]=s1[q]=s2[q]=0.f; }

    for (int cs = base; cs < end; cs += ECAP) {
        int ce = min(cs + ECAP, end);
        __syncthreads();
        for (int t = cs + tid; t < ce; t += 256)
            ebuf[t - cs] = bin4[(size_t)b*EE + t];
        __syncthreads();
#pragma unroll
        for (int q = 0; q < 4; q++) {
            int nl = w*4 + q;
            int js = max(soff[nl], cs);
            int je = min(soff[nl+1], ce);
#pragma unroll 2
            for (int j = js; j < je; j++) {
                float4 e = ebuf[j - cs];
                int src = __float_as_int(e.x);
                float xs = xTb[(size_t)src*CC];
                a0[q] = fmaf(xs, e.y, a0[q]);
                a1[q] = fmaf(xs, e.z, a1[q]);
                a2[q] = fmaf(xs, e.w, a2[q]);
                s0[q] += e.y; s1[q] += e.z; s2[q] += e.w;
            }
        }
    }
    __syncthreads();
#pragma unroll
    for (int q = 0; q < 4; q++) {
        int nl = w*4 + q;
        float xtgt = xTb[(size_t)(n0 + nl)*CC];
        gl[nl][lane*3+0] = a0[q] - xtgt*s0[q];
        gl[nl][lane*3+1] = a1[q] - xtgt*s1[q];
        gl[nl][lane*3+2] = a2[q] - xtgt*s2[q];
    }
    __syncthreads();
    for (int t = tid; t < 16*192; t += 256) {
        int g = t >> 4, nl = t & 15;
        gradfT[((size_t)b*192+g)*NN + n0 + nl] = gl[nl][g];
    }
}

// ---- fused final: x1 + x2 + x3 + x4 (h computed in-block) -> exact GELU ----
// 1024 threads = 16 waves, wave w owns o/i rows 4w..4w+3; lane = n.
// 512 blocks x 16 waves -> 32 waves/CU (grid was the occupancy cap before).
__global__ void __launch_bounds__(1024) k_c(const float* __restrict__ x,
                                            const float* __restrict__ nodes,
                                            const float* __restrict__ modes,
                                            const float* __restrict__ geo,
                                            const float* __restrict__ fTc,
                                            const float* __restrict__ fTs,
                                            const float* __restrict__ f0,
                                            const float* __restrict__ WT,
                                            const float* __restrict__ wxT,
                                            const float* __restrict__ gwxT,
                                            const float* __restrict__ w2T,
                                            const float* __restrict__ gwT,
                                            const float* __restrict__ gradfT,
                                            float* __restrict__ out) {
    int blk = blockIdx.x;
    int b = blk / (NN/64);
    int n0 = (blk % (NN/64)) * 64;
    int tid = threadIdx.x;
    int lane = tid & 63;
    int w = __builtin_amdgcn_readfirstlane(tid >> 6);    // 0..15
    int o0 = w * 4;
    int n = n0 + lane;
    __shared__ __half2 cs[KK*64];    // {cos,sin} packed, 32 KB
    __shared__ float   xl[64*64];    // x[j][n] tile, 16 KB
    __shared__ float   hl[64*64];    // h[i][n] tile, 16 KB

    // stage x tile (each wave loads 4 j-rows, coalesced in n)
#pragma unroll
    for (int p = 0; p < 4; p++) {
        int j = p*16 + w;
        xl[j*64 + lane] = x[((size_t)b*CC + j)*NN + n];
    }
    // cos/sin tile
    float nd0 = nodes[((size_t)b*NN+n)*3+0];
    float nd1 = nodes[((size_t)b*NN+n)*3+1];
    float nd2 = nodes[((size_t)b*NN+n)*3+2];
#pragma unroll
    for (int r = 0; r < 8; r++) {
        int k = r*16 + w;
        float t = nd0*modes[k*3+0] + nd1*modes[k*3+1] + nd2*modes[k*3+2];
        cs[k*64+lane] = __floats2half2_rn(__cosf(t), __sinf(t));
    }
    __syncthreads();

    float acc[4], xw[4];
    const float* __restrict__ f0p = &f0[b*CC + o0];
#pragma unroll
    for (int oo = 0; oo < 4; oo++) { acc[oo] = f0p[oo]; xw[oo] = 0.f; }

    // merged j-loop: x2 (W) and h-precursor (wx) share the x-tile read
    for (int j = 0; j < CC; j++) {
        float xv = xl[j*64 + lane];
        const float* __restrict__ wr  = &WT[j*CC + o0];
        const float* __restrict__ wxr = &wxT[j*CC + o0];
#pragma unroll
        for (int oo = 0; oo < 4; oo++) {
            acc[oo] = fmaf(wr[oo],  xv, acc[oo]);
            xw[oo]  = fmaf(wxr[oo], xv, xw[oo]);
        }
    }
    // softsign gate -> h tile (i-rows == this wave's o-rows)
    float g0 = geo[((size_t)b*GG+0)*NN + n];
    float g1 = geo[((size_t)b*GG+1)*NN + n];
    float g2 = geo[((size_t)b*GG+2)*NN + n];
#pragma unroll
    for (int oo = 0; oo < 4; oo++) {
        int i = o0 + oo;
        float t = gwxT[0*CC+i]*g0 + gwxT[1*CC+i]*g1 + gwxT[2*CC+i]*g2;
        float ssv = t / (1.f + fabsf(t));
        hl[i*64 + lane] = ssv * xw[oo];
    }
    __syncthreads();

    // x1: spectral inverse
    for (int k = 0; k < KK; k++) {
        __half2 h = cs[k*64 + lane];
        float cv = __low2float(h);
        float sv = __high2float(h);
        const float* __restrict__ fc = &fTc[(b*KK+k)*CC + o0];
        const float* __restrict__ fs = &fTs[(b*KK+k)*CC + o0];
#pragma unroll
        for (int oo = 0; oo < 4; oo++)
            acc[oo] += fc[oo]*cv - fs[oo]*sv;
    }
    // x4: w2 @ h (h from LDS)
    for (int i = 0; i < CC; i++) {
        float hv = hl[i*64 + lane];
        const float* __restrict__ wr = &w2T[i*CC + o0];
#pragma unroll
        for (int oo = 0; oo < 4; oo++) acc[oo] = fmaf(wr[oo], hv, acc[oo]);
    }
    // x3: gw @ gradf
    for (int g = 0; g < 192; g++) {
        float gv = gradfT[((size_t)b*192+g)*NN + n];
        const float* __restrict__ wr = &gwT[g*CC + o0];
#pragma unroll
        for (int oo = 0; oo < 4; oo++) acc[oo] = fmaf(wr[oo], gv, acc[oo]);
    }
#pragma unroll
    for (int oo = 0; oo < 4; oo++) {
        float v = acc[oo];
        float r = 0.5f * v * (1.f + erff(v * 0.70710678118654752f));
        out[((size_t)b*CC + o0 + oo)*NN + n] = r;
    }
}

extern "C" void kernel_launch(void* const* d_in, const int* in_sizes, int n_in,
                              void* d_out, int out_size, void* d_ws, size_t ws_size,
                              hipStream_t stream) {
    const float* x      = (const float*)d_in[0];
    const float* nodes  = (const float*)d_in[1];
    const float* nwt    = (const float*)d_in[2];
    const float* geo    = (const float*)d_in[3];
    const int*   edges  = (const int*)d_in[4];
    const float* egw    = (const float*)d_in[5];
    const float* modes  = (const float*)d_in[6];
    const float* wc     = (const float*)d_in[7];
    const float* wsw    = (const float*)d_in[8];
    const float* w0     = (const float*)d_in[9];
    const float* W      = (const float*)d_in[10];
    const float* gw     = (const float*)d_in[11];
    const float* geo_wx = (const float*)d_in[12];
    const float* wx     = (const float*)d_in[13];
    const float* w2     = (const float*)d_in[14];

    float* ws   = (float*)d_ws;
    float* xT   = ws + OFF_XT;
    float* pc   = ws + OFF_PC;
    float* ps   = ws + OFF_PS;
    float* Ac   = ws + OFF_AC;
    float* As   = ws + OFF_AS;
    float* fTc  = ws + OFF_FTC;
    float* fTs  = ws + OFF_FTS;
    float* f0   = ws + OFF_F0;
    float* x0   = ws + OFF_X0;
    int*  counts = (int*)(ws + OFF_CNT);
    int*  offs   = (int*)(ws + OFF_OFFS);
    int*  cur    = (int*)(ws + OFF_CUR);
    float4* bin4 = (float4*)(ws + OFF_BIN4);
    float* gradfT = ws + OFF_GRT;
    float* WT   = ws + OFF_WT;
    float* wxT  = ws + OFF_WXT;
    float* w2T  = ws + OFF_W2T;
    float* gwT  = ws + OFF_GWT;
    float* gwxT = ws + OFF_GWXT;
    float* out  = (float*)d_out;

    hipMemsetAsync(counts, 0, (size_t)(BB*NN)*sizeof(int), stream);

    k_prep <<<48, 256, 0, stream>>>(W, gw, geo_wx, wx, w2, WT, wxT, w2T, gwT, gwxT);
    k_xt   <<<BB*(NN/64), 256, 0, stream>>>(x, xT);
    k_x0   <<<BB*CC, 256, 0, stream>>>(x, nwt, x0);
    k_a    <<<dim3(BB*PP, 2), 256, 0, stream>>>(xT, nodes, nwt, modes, pc, ps);
    k_ared <<<(BB*CC*KK)/256, 256, 0, stream>>>(pc, ps, Ac, As);
    k_b    <<<BB*CC, 128, 0, stream>>>(Ac, As, wc, wsw, w0, x0, fTc, fTs, f0);
    k_count<<<(BB*EE)/256, 256, 0, stream>>>(edges, counts);
    k_scan <<<BB, 1024, 0, stream>>>(counts, offs, cur);
    k_fill <<<(BB*EE)/256, 256, 0, stream>>>(edges, egw, cur, bin4);
    k_edge <<<BB*(NN/16), 256, 0, stream>>>(xT, offs, bin4, gradfT);
    k_c    <<<BB*(NN/64), 1024, 0, stream>>>(x, nodes, modes, geo, fTc, fTs, f0,
                                             WT, wxT, gwxT, w2T, gwT, gradfT, out);
}

// Round 6
// 346.517 us; speedup vs baseline: 1.2267x; 1.1865x over previous
//
#include <hip/hip_runtime.h>
#include <hip/hip_fp16.h>
#include <math.h>

#define BB 2
#define CC 64
#define NN 16384
#define DD 3
#define KK 128
#define EE 262144
#define GG 3
#define PP 128           // n-chunks for spectral-forward partials (512 blocks -> 2/CU)
#define LL (NN/PP)       // 128 n per chunk
#define KTOT 576         // concat K of final GEMM: 128 cos + 128 sin + 64 x + 64 h + 192 gradf

// ---- workspace layout (float elements) ----
constexpr size_t OFF_XT   = 0;                                  // xT[b][n][i]
constexpr size_t OFF_PC   = OFF_XT   + (size_t)BB*NN*CC;        // partial A_c
constexpr size_t OFF_PS   = OFF_PC   + (size_t)BB*PP*CC*KK;     // partial A_s
// bin4 aliases pc/ps (pc/ps dead after k_ared; k_fill runs later in-stream)
constexpr size_t OFF_BIN4 = OFF_PC;                             // float4 binlist[b][E] (8MB == PC)
constexpr size_t OFF_AC   = OFF_PS   + (size_t)BB*PP*CC*KK;     // A_c[b][i][k]
constexpr size_t OFF_AS   = OFF_AC   + (size_t)BB*CC*KK;
constexpr size_t OFF_FTC  = OFF_AS   + (size_t)BB*CC*KK;        // 2*f_c[b][k][o]
constexpr size_t OFF_FTS  = OFF_FTC  + (size_t)BB*KK*CC;        // 2*f_s[b][k][o]
constexpr size_t OFF_F0   = OFF_FTS  + (size_t)BB*KK*CC;        // f0[b][o]
constexpr size_t OFF_X0   = OFF_F0   + (size_t)BB*CC;           // x0[b][i]
constexpr size_t OFF_CNT  = OFF_X0   + (size_t)BB*CC;           // int counts (zeroed)
constexpr size_t OFF_OFFS = OFF_CNT  + (size_t)BB*NN;           // int offsets
constexpr size_t OFF_CUR  = OFF_OFFS + (size_t)BB*NN;           // int cursor
constexpr size_t OFF_GRT  = OFF_CUR  + (size_t)BB*NN;           // gradfT[b][g][n]
constexpr size_t OFF_H    = OFF_GRT  + (size_t)BB*192*NN;       // h[b][i][n]
constexpr size_t OFF_APAN = OFF_H    + (size_t)BB*CC*NN;        // Apan[b][576][64]
constexpr size_t OFF_WT   = OFF_APAN + (size_t)BB*KTOT*CC;      // W^T  [j][o]
constexpr size_t OFF_WXT  = OFF_WT   + (size_t)CC*CC;           // wx^T [j][i]
constexpr size_t OFF_W2T  = OFF_WXT  + (size_t)CC*CC;           // w2^T [i][o]
constexpr size_t OFF_GWT  = OFF_W2T  + (size_t)CC*CC;           // gw^T [g][o]
constexpr size_t OFF_GWXT = OFF_GWT  + (size_t)CC*CC*DD;        // geo_wx^T [g][i]

// ---- small transposes ----
__global__ void k_prep(const float* __restrict__ W, const float* __restrict__ gw,
                       const float* __restrict__ geo_wx, const float* __restrict__ wx,
                       const float* __restrict__ w2,
                       float* WT, float* wxT, float* w2T, float* gwT, float* gwxT) {
    int idx = blockIdx.x*256 + threadIdx.x;
    if (idx < CC*CC) { int j = idx>>6, o = idx&63; WT[idx]  = W[o*CC+j];  }
    if (idx < CC*CC) { int j = idx>>6, i = idx&63; wxT[idx] = wx[i*CC+j]; }
    if (idx < CC*CC) { int i = idx>>6, o = idx&63; w2T[idx] = w2[o*CC+i]; }
    if (idx < CC*CC*DD) { int g = idx>>6, o = idx&63; gwT[idx] = gw[o*(CC*DD)+g]; }
    if (idx < GG*CC) { int g = idx>>6, i = idx&63; gwxT[idx] = geo_wx[i*GG+g]; }
}

// ---- transpose x -> xT[b][n][i] ----
__global__ void __launch_bounds__(256) k_xt(const float* __restrict__ x,
                                            float* __restrict__ xT) {
    int blk = blockIdx.x;
    int b = blk / (NN/64);
    int n0 = (blk % (NN/64)) * 64;
    __shared__ float tile[64][65];
    int tid = threadIdx.x;
    int c = tid & 63, r4 = tid >> 6;
    for (int rr = 0; rr < 16; rr++) {
        int i = r4*16 + rr;
        tile[i][c] = x[((size_t)b*CC + i)*NN + n0 + c];
    }
    __syncthreads();
    for (int rr = 0; rr < 16; rr++) {
        int nn = r4*16 + rr;
        xT[((size_t)b*NN + n0 + nn)*CC + c] = tile[c][nn];
    }
}

// ---- x0[b][i] = sum_n x[b,i,n] * nw[b,n] ----
__global__ void __launch_bounds__(256) k_x0(const float* __restrict__ x,
                                            const float* __restrict__ nwt,
                                            float* __restrict__ x0) {
    int b = blockIdx.x >> 6;
    int i = blockIdx.x & 63;
    int tid = threadIdx.x;
    const float4* __restrict__ xr = (const float4*)&x[((size_t)b*CC + i)*NN];
    const float4* __restrict__ wr = (const float4*)&nwt[(size_t)b*NN];
    float s = 0.f;
    for (int t = tid; t < NN/4; t += 256) {
        float4 xv = xr[t];
        float4 wv = wr[t];
        s += xv.x*wv.x + xv.y*wv.y + xv.z*wv.z + xv.w*wv.w;
    }
    __shared__ float red[256];
    red[tid] = s;
    __syncthreads();
    for (int off = 128; off > 0; off >>= 1) {
        if (tid < off) red[tid] += red[tid+off];
        __syncthreads();
    }
    if (tid == 0) x0[b*CC + i] = red[0];
}

// ---- spectral forward partials: A_c/A_s[b][i][k] over n-chunks ----
__global__ void __launch_bounds__(256) k_a(const float* __restrict__ xT,
                                           const float* __restrict__ nodes,
                                           const float* __restrict__ nwt,
                                           const float* __restrict__ modes,
                                           float* __restrict__ pc, float* __restrict__ ps) {
    int bc = blockIdx.x;
    int b = bc / PP, chunk = bc % PP;
    int tid = threadIdx.x;
    int lane = tid & 63;
    int w = tid >> 6;
    int khalf = w & 1;
    int ig = blockIdx.y*2 + (w >> 1);
    int k = khalf*64 + lane;
    int i0 = __builtin_amdgcn_readfirstlane(ig * 16);
    float m0 = modes[k*3+0], m1 = modes[k*3+1], m2 = modes[k*3+2];
    float ac[16], as[16];
#pragma unroll
    for (int j = 0; j < 16; j++) { ac[j]=0.f; as[j]=0.f; }
    int nbase = chunk*LL;
    for (int t = 0; t < LL; t++) {
        int n = nbase + t;
        float nd0 = nodes[(b*NN+n)*3+0], nd1 = nodes[(b*NN+n)*3+1], nd2 = nodes[(b*NN+n)*3+2];
        float nw = nwt[b*NN+n];
        float tt = nd0*m0 + nd1*m1 + nd2*m2;
        float cv = __cosf(tt) * nw, sv = __sinf(tt) * nw;
        const float* __restrict__ xrow = &xT[((size_t)b*NN+n)*CC + i0];
#pragma unroll
        for (int j = 0; j < 16; j++) {
            float xv = xrow[j];
            ac[j] = fmaf(xv, cv, ac[j]);
            as[j] = fmaf(xv, sv, as[j]);
        }
    }
    int base = (b*PP + chunk)*CC;
#pragma unroll
    for (int j = 0; j < 16; j++) {
        pc[(size_t)(base + i0 + j)*KK + k] = ac[j];
        ps[(size_t)(base + i0 + j)*KK + k] = as[j];
    }
}

__global__ void k_ared(const float* __restrict__ pc, const float* __restrict__ ps,
                       float* __restrict__ Ac, float* __restrict__ As) {
    int idx = blockIdx.x*256 + threadIdx.x;
    if (idx >= BB*CC*KK) return;
    int b = idx / (CC*KK);
    int r = idx % (CC*KK);
    float sc = 0.f, ss = 0.f;
    for (int ch = 0; ch < PP; ch++) {
        size_t o = ((size_t)(b*PP + ch)*CC)*KK + r;
        sc += pc[o]; ss += ps[o];
    }
    Ac[idx] = sc; As[idx] = ss;
}

// ---- channel mix -> 2*f_c, 2*f_s in [b][k][o] layout, + f0 ----
__global__ void k_b(const float* __restrict__ Ac, const float* __restrict__ As,
                    const float* __restrict__ wc, const float* __restrict__ wsw,
                    const float* __restrict__ w0, const float* __restrict__ x0,
                    float* __restrict__ fTc, float* __restrict__ fTs, float* __restrict__ f0) {
    int b = blockIdx.x / CC, o = blockIdx.x % CC;
    int k = threadIdx.x;
    float fc = 0.f, fs = 0.f;
    for (int i = 0; i < CC; i++) {
        float a_c = Ac[(b*CC+i)*KK + k];
        float a_s = As[(b*CC+i)*KK + k];
        float wcc = wc[((size_t)(i*CC+o))*KK + k];
        float wss = wsw[((size_t)(i*CC+o))*KK + k];
        fc += a_c*wcc + a_s*wss;
        fs += a_c*wss - a_s*wcc;
    }
    fTc[(b*KK+k)*CC + o] = 2.f*fc;
    fTs[(b*KK+k)*CC + o] = 2.f*fs;
    if (threadIdx.x == 0) {
        float acc = 0.f;
        for (int i = 0; i < CC; i++) acc += x0[b*CC+i]*w0[i*CC+o];
        f0[b*CC+o] = acc;
    }
}

// ---- build A-panel [b][576][64] for the final GEMM ----
__global__ void k_apan(const float* __restrict__ fTc, const float* __restrict__ fTs,
                       const float* __restrict__ WT, const float* __restrict__ w2T,
                       const float* __restrict__ gwT, float* __restrict__ Apan) {
    int idx = blockIdx.x*256 + threadIdx.x;       // over BB*576*64
    if (idx >= BB*KTOT*CC) return;
    int b = idx / (KTOT*CC);
    int r = idx % (KTOT*CC);
    int k = r >> 6, o = r & 63;
    float v;
    if (k < 128)      v =  fTc[(b*KK + k)*CC + o];
    else if (k < 256) v = -fTs[(b*KK + (k-128))*CC + o];
    else if (k < 320) v = WT[(k-256)*CC + o];
    else if (k < 384) v = w2T[(k-320)*CC + o];
    else              v = gwT[(k-384)*CC + o];
    Apan[idx] = v;
}

// ---- edge binning ----
__global__ void k_count(const int* __restrict__ edges, int* __restrict__ counts) {
    int idx = blockIdx.x*256 + threadIdx.x;
    if (idx >= BB*EE) return;
    int tgt = edges[(size_t)idx*2 + 0];
    int b = idx / EE;
    atomicAdd(&counts[b*NN + tgt], 1);
}

__global__ void __launch_bounds__(1024) k_scan(const int* __restrict__ counts,
                                               int* __restrict__ offsets, int* __restrict__ cursor) {
    __shared__ int part[1024];
    int b = blockIdx.x;
    int tid = threadIdx.x;
    int base = tid*16;
    int loc[16]; int s = 0;
    for (int j = 0; j < 16; j++) { loc[j] = counts[b*NN + base + j]; s += loc[j]; }
    part[tid] = s;
    __syncthreads();
    for (int off = 1; off < 1024; off <<= 1) {
        int v = (tid >= off) ? part[tid-off] : 0;
        __syncthreads();
        part[tid] += v;
        __syncthreads();
    }
    int excl = part[tid] - s;
    for (int j = 0; j < 16; j++) {
        offsets[b*NN+base+j] = excl;
        cursor[b*NN+base+j]  = excl;
        excl += loc[j];
    }
}

// ---- fill bins with packed {src, w0, w1, w2} entries ----
__global__ void k_fill(const int* __restrict__ edges, const float* __restrict__ egw,
                       int* __restrict__ cursor, float4* __restrict__ bin4) {
    int idx = blockIdx.x*256 + threadIdx.x;
    if (idx >= BB*EE) return;
    int b = idx / EE;
    int tgt = edges[(size_t)idx*2+0];
    int src = edges[(size_t)idx*2+1];
    const float* __restrict__ ew = &egw[(size_t)idx*3];
    float w0 = ew[0], w1 = ew[1], w2 = ew[2];
    int pos = atomicAdd(&cursor[b*NN+tgt], 1);
    bin4[(size_t)b*EE + pos] = make_float4(__int_as_float(src), w0, w1, w2);
}

// ---- per-node edge accumulate -> gradfT[b][g][n] ----
#define ECAP 1024
__global__ void __launch_bounds__(256) k_edge(const float* __restrict__ xT,
                                              const int* __restrict__ offsets,
                                              const float4* __restrict__ bin4,
                                              float* __restrict__ gradfT) {
    int blk = blockIdx.x;
    int b = blk / (NN/16);
    int n0 = (blk % (NN/16)) * 16;
    int tid = threadIdx.x;
    int lane = tid & 63;
    int w = tid >> 6;                 // 4 waves, 4 nodes each
    __shared__ float4 ebuf[ECAP];
    __shared__ float gl[16][193];
    __shared__ int soff[17];
    if (tid < 16) soff[tid] = offsets[b*NN + n0 + tid];
    if (tid == 16) soff[16] = (n0 + 16 < NN) ? offsets[b*NN + n0 + 16] : EE;
    __syncthreads();
    int base = soff[0];
    int end  = soff[16];
    const float* __restrict__ xTb = &xT[(size_t)b*NN*CC + lane];

    float a0[4], a1[4], a2[4], s0[4], s1[4], s2[4];
#pragma unroll
    for (int q = 0; q < 4; q++) { a0[q]=a1[q]=a2[q]=0.f; s0[q]=s1[q]=s2[q]=0.f; }

    for (int cs = base; cs < end; cs += ECAP) {
        int ce = min(cs + ECAP, end);
        __syncthreads();
        for (int t = cs + tid; t < ce; t += 256)
            ebuf[t - cs] = bin4[(size_t)b*EE + t];
        __syncthreads();
#pragma unroll
        for (int q = 0; q < 4; q++) {
            int nl = w*4 + q;
            int js = max(soff[nl], cs);
            int je = min(soff[nl+1], ce);
#pragma unroll 2
            for (int j = js; j < je; j++) {
                float4 e = ebuf[j - cs];
                int src = __float_as_int(e.x);
                float xs = xTb[(size_t)src*CC];
                a0[q] = fmaf(xs, e.y, a0[q]);
                a1[q] = fmaf(xs, e.z, a1[q]);
                a2[q] = fmaf(xs, e.w, a2[q]);
                s0[q] += e.y; s1[q] += e.z; s2[q] += e.w;
            }
        }
    }
    __syncthreads();
#pragma unroll
    for (int q = 0; q < 4; q++) {
        int nl = w*4 + q;
        float xtgt = xTb[(size_t)(n0 + nl)*CC];
        gl[nl][lane*3+0] = a0[q] - xtgt*s0[q];
        gl[nl][lane*3+1] = a1[q] - xtgt*s1[q];
        gl[nl][lane*3+2] = a2[q] - xtgt*s2[q];
    }
    __syncthreads();
    for (int t = tid; t < 16*192; t += 256) {
        int g = t >> 4, nl = t & 15;
        gradfT[((size_t)b*192+g)*NN + n0 + nl] = gl[nl][g];
    }
}

// ---- h[b][i][n] = softsign(geo_wx@geo) * (wx@x) ----
__global__ void __launch_bounds__(256) k_h(const float* __restrict__ x,
                                           const float* __restrict__ geo,
                                           const float* __restrict__ wxT,
                                           const float* __restrict__ gwxT,
                                           float* __restrict__ hbuf) {
    int blk = blockIdx.x;
    int b = blk / (NN/256);
    int n0 = (blk % (NN/256)) * 256;
    int i0 = blockIdx.y * 32;
    int n = n0 + threadIdx.x;
    float xw[32];
#pragma unroll
    for (int ii = 0; ii < 32; ii++) xw[ii] = 0.f;
    for (int j = 0; j < CC; j++) {
        float xv = x[((size_t)b*CC+j)*NN + n];
        const float* __restrict__ wr = &wxT[j*CC + i0];
#pragma unroll
        for (int ii = 0; ii < 32; ii++) xw[ii] = fmaf(wr[ii], xv, xw[ii]);
    }
    float g0 = geo[((size_t)b*GG+0)*NN + n];
    float g1 = geo[((size_t)b*GG+1)*NN + n];
    float g2 = geo[((size_t)b*GG+2)*NN + n];
#pragma unroll
    for (int ii = 0; ii < 32; ii++) {
        int i = i0 + ii;
        float t = gwxT[0*CC+i]*g0 + gwxT[1*CC+i]*g1 + gwxT[2*CC+i]*g2;
        float ssv = t / (1.f + fabsf(t));
        hbuf[((size_t)b*CC+i)*NN + n] = ssv * xw[ii];
    }
}

// ---- final fused GEMM: out = gelu(Apan^T · B + f0), K=576, tile 64o x 64n ----
// 256 threads (tx,ty) = (n/4, o/4); thread tile 4x4; A/B chunks staged in LDS.
#define KC 64
__global__ void __launch_bounds__(256) k_gemm(const float* __restrict__ x,
                                              const float* __restrict__ nodes,
                                              const float* __restrict__ modes,
                                              const float* __restrict__ hbuf,
                                              const float* __restrict__ gradfT,
                                              const float* __restrict__ Apan,
                                              const float* __restrict__ f0,
                                              float* __restrict__ out) {
    int blk = blockIdx.x;
    int b  = blk >> 8;                 // 256 n-tiles per batch
    int n0 = (blk & 255) * 64;
    int tid = threadIdx.x;
    int tx = tid & 15;                 // n / 4
    int ty = tid >> 4;                 // o / 4
    __shared__ float As[KC*64];
    __shared__ float Bs[KC*64];
    __shared__ float ndl[64*3];
    if (tid < 192) ndl[tid] = nodes[((size_t)b*NN + n0)*3 + tid];

    float acc[4][4];
#pragma unroll
    for (int oo = 0; oo < 4; oo++) {
        float fv = f0[b*CC + ty*4 + oo];
#pragma unroll
        for (int nn = 0; nn < 4; nn++) acc[oo][nn] = fv;
    }
    const float* __restrict__ Ab = Apan + (size_t)b*KTOT*CC;

    for (int c = 0; c < KTOT/KC; c++) {
        int k0 = c*KC;
        __syncthreads();
        // A chunk: linear float4 copy
        {
            const float4* __restrict__ src = (const float4*)(Ab + (size_t)k0*64);
            float4* dst = (float4*)As;
            for (int s = tid; s < KC*64/4; s += 256) dst[s] = src[s];
        }
        // B chunk
        if (c < 4) {
            bool isCos = (c < 2);
            int kabs0 = (c & 1) * 64;
#pragma unroll
            for (int s = 0; s < 16; s++) {
                int e = tid + s*256;
                int r = e >> 6, n = e & 63;
                int k = kabs0 + r;
                float m0 = modes[k*3+0], m1 = modes[k*3+1], m2 = modes[k*3+2];
                float t = ndl[n*3+0]*m0 + ndl[n*3+1]*m1 + ndl[n*3+2]*m2;
                Bs[e] = isCos ? __cosf(t) : __sinf(t);
            }
        } else {
            const float* __restrict__ src;
            if (c == 4)      src = &x[(size_t)b*CC*NN];
            else if (c == 5) src = &hbuf[(size_t)b*CC*NN];
            else             src = &gradfT[((size_t)b*192 + (c-6)*64)*NN];
#pragma unroll
            for (int s = 0; s < 16; s++) {
                int e = tid + s*256;
                int r = e >> 6, n = e & 63;
                Bs[e] = src[(size_t)r*NN + n0 + n];
            }
        }
        __syncthreads();
#pragma unroll 4
        for (int kk = 0; kk < KC; kk++) {
            float4 a4 = *(const float4*)&As[kk*64 + ty*4];
            float4 b4 = *(const float4*)&Bs[kk*64 + tx*4];
            float av[4] = {a4.x, a4.y, a4.z, a4.w};
            float bv[4] = {b4.x, b4.y, b4.z, b4.w};
#pragma unroll
            for (int oo = 0; oo < 4; oo++)
#pragma unroll
                for (int nn = 0; nn < 4; nn++)
                    acc[oo][nn] = fmaf(av[oo], bv[nn], acc[oo][nn]);
        }
    }
    // epilogue: exact GELU + float4 store
#pragma unroll
    for (int oo = 0; oo < 4; oo++) {
        int o = ty*4 + oo;
        float4 r4;
        float* rp = (float*)&r4;
#pragma unroll
        for (int nn = 0; nn < 4; nn++) {
            float v = acc[oo][nn];
            rp[nn] = 0.5f * v * (1.f + erff(v * 0.70710678118654752f));
        }
        *(float4*)&out[((size_t)b*CC + o)*NN + n0 + tx*4] = r4;
    }
}

extern "C" void kernel_launch(void* const* d_in, const int* in_sizes, int n_in,
                              void* d_out, int out_size, void* d_ws, size_t ws_size,
                              hipStream_t stream) {
    const float* x      = (const float*)d_in[0];
    const float* nodes  = (const float*)d_in[1];
    const float* nwt    = (const float*)d_in[2];
    const float* geo    = (const float*)d_in[3];
    const int*   edges  = (const int*)d_in[4];
    const float* egw    = (const float*)d_in[5];
    const float* modes  = (const float*)d_in[6];
    const float* wc     = (const float*)d_in[7];
    const float* wsw    = (const float*)d_in[8];
    const float* w0     = (const float*)d_in[9];
    const float* W      = (const float*)d_in[10];
    const float* gw     = (const float*)d_in[11];
    const float* geo_wx = (const float*)d_in[12];
    const float* wx     = (const float*)d_in[13];
    const float* w2     = (const float*)d_in[14];

    float* ws   = (float*)d_ws;
    float* xT   = ws + OFF_XT;
    float* pc   = ws + OFF_PC;
    float* ps   = ws + OFF_PS;
    float* Ac   = ws + OFF_AC;
    float* As   = ws + OFF_AS;
    float* fTc  = ws + OFF_FTC;
    float* fTs  = ws + OFF_FTS;
    float* f0   = ws + OFF_F0;
    float* x0   = ws + OFF_X0;
    int*  counts = (int*)(ws + OFF_CNT);
    int*  offs   = (int*)(ws + OFF_OFFS);
    int*  cur    = (int*)(ws + OFF_CUR);
    float4* bin4 = (float4*)(ws + OFF_BIN4);
    float* gradfT = ws + OFF_GRT;
    float* hbuf   = ws + OFF_H;
    float* Apan   = ws + OFF_APAN;
    float* WT   = ws + OFF_WT;
    float* wxT  = ws + OFF_WXT;
    float* w2T  = ws + OFF_W2T;
    float* gwT  = ws + OFF_GWT;
    float* gwxT = ws + OFF_GWXT;
    float* out  = (float*)d_out;

    hipMemsetAsync(counts, 0, (size_t)(BB*NN)*sizeof(int), stream);

    k_prep <<<48, 256, 0, stream>>>(W, gw, geo_wx, wx, w2, WT, wxT, w2T, gwT, gwxT);
    k_xt   <<<BB*(NN/64), 256, 0, stream>>>(x, xT);
    k_x0   <<<BB*CC, 256, 0, stream>>>(x, nwt, x0);
    k_a    <<<dim3(BB*PP, 2), 256, 0, stream>>>(xT, nodes, nwt, modes, pc, ps);
    k_ared <<<(BB*CC*KK)/256, 256, 0, stream>>>(pc, ps, Ac, As);
    k_b    <<<BB*CC, 128, 0, stream>>>(Ac, As, wc, wsw, w0, x0, fTc, fTs, f0);
    k_apan <<<(BB*KTOT*CC + 255)/256, 256, 0, stream>>>(fTc, fTs, WT, w2T, gwT, Apan);
    k_count<<<(BB*EE)/256, 256, 0, stream>>>(edges, counts);
    k_scan <<<BB, 1024, 0, stream>>>(counts, offs, cur);
    k_fill <<<(BB*EE)/256, 256, 0, stream>>>(edges, egw, cur, bin4);
    k_edge <<<BB*(NN/16), 256, 0, stream>>>(xT, offs, bin4, gradfT);
    k_h    <<<dim3(BB*(NN/256), 2), 256, 0, stream>>>(x, geo, wxT, gwxT, hbuf);
    k_gemm <<<BB*(NN/64), 256, 0, stream>>>(x, nodes, modes, hbuf, gradfT, Apan, f0, out);
}

// Round 8
// 312.081 us; speedup vs baseline: 1.3620x; 1.1103x over previous
//
#include <hip/hip_runtime.h>
#include <hip/hip_fp16.h>
#include <math.h>

#define BB 2
#define CC 64
#define NN 16384
#define DD 3
#define KK 128
#define EE 262144
#define GG 3
#define PP 128           // n-chunks for spectral-forward partials
#define LL (NN/PP)       // 128 n per chunk
#define KTOT 576         // concat K: 256 interleaved cos/sin + 64 x + 64 h + 192 gradf

// ---- workspace layout (float elements) ----
constexpr size_t OFF_XT   = 0;                                  // xT[b][n][i]
constexpr size_t OFF_PC   = OFF_XT   + (size_t)BB*NN*CC;        // partial A_c
constexpr size_t OFF_PS   = OFF_PC   + (size_t)BB*PP*CC*KK;     // partial A_s
constexpr size_t OFF_BIN4 = OFF_PC;                             // float4 binlist[b][E] (aliases pc/ps)
constexpr size_t OFF_AC   = OFF_PS   + (size_t)BB*PP*CC*KK;     // A_c[b][i][k]
constexpr size_t OFF_AS   = OFF_AC   + (size_t)BB*CC*KK;
constexpr size_t OFF_FTC  = OFF_AS   + (size_t)BB*CC*KK;        // 2*f_c[b][k][o]
constexpr size_t OFF_FTS  = OFF_FTC  + (size_t)BB*KK*CC;        // 2*f_s[b][k][o]
constexpr size_t OFF_F0   = OFF_FTS  + (size_t)BB*KK*CC;        // f0[b][o]
constexpr size_t OFF_X0   = OFF_F0   + (size_t)BB*CC;           // x0[b][i]
constexpr size_t OFF_CNT  = OFF_X0   + (size_t)BB*CC;           // int counts (zeroed)
constexpr size_t OFF_OFFS = OFF_CNT  + (size_t)BB*NN;           // int offsets
constexpr size_t OFF_CUR  = OFF_OFFS + (size_t)BB*NN;           // int cursor
constexpr size_t OFF_GRT  = OFF_CUR  + (size_t)BB*NN;           // gradfT[b][g][n]
constexpr size_t OFF_APAN = OFF_GRT  + (size_t)BB*192*NN;       // Apan[b][576][64]
constexpr size_t OFF_WT   = OFF_APAN + (size_t)BB*KTOT*CC;      // W^T  [j][o]
constexpr size_t OFF_WXT  = OFF_WT   + (size_t)CC*CC;           // wx^T [j][i]
constexpr size_t OFF_W2T  = OFF_WXT  + (size_t)CC*CC;           // w2^T [i][o]
constexpr size_t OFF_GWT  = OFF_W2T  + (size_t)CC*CC;           // gw^T [g][o]
constexpr size_t OFF_GWXT = OFF_GWT  + (size_t)CC*CC*DD;        // geo_wx^T [g][i]

// ---- small transposes ----
__global__ void k_prep(const float* __restrict__ W, const float* __restrict__ gw,
                       const float* __restrict__ geo_wx, const float* __restrict__ wx,
                       const float* __restrict__ w2,
                       float* WT, float* wxT, float* w2T, float* gwT, float* gwxT) {
    int idx = blockIdx.x*256 + threadIdx.x;
    if (idx < CC*CC) { int j = idx>>6, o = idx&63; WT[idx]  = W[o*CC+j];  }
    if (idx < CC*CC) { int j = idx>>6, i = idx&63; wxT[idx] = wx[i*CC+j]; }
    if (idx < CC*CC) { int i = idx>>6, o = idx&63; w2T[idx] = w2[o*CC+i]; }
    if (idx < CC*CC*DD) { int g = idx>>6, o = idx&63; gwT[idx] = gw[o*(CC*DD)+g]; }
    if (idx < GG*CC) { int g = idx>>6, i = idx&63; gwxT[idx] = geo_wx[i*GG+g]; }
}

// ---- transpose x -> xT[b][n][i] ----
__global__ void __launch_bounds__(256) k_xt(const float* __restrict__ x,
                                            float* __restrict__ xT) {
    int blk = blockIdx.x;
    int b = blk / (NN/64);
    int n0 = (blk % (NN/64)) * 64;
    __shared__ float tile[64][65];
    int tid = threadIdx.x;
    int c = tid & 63, r4 = tid >> 6;
    for (int rr = 0; rr < 16; rr++) {
        int i = r4*16 + rr;
        tile[i][c] = x[((size_t)b*CC + i)*NN + n0 + c];
    }
    __syncthreads();
    for (int rr = 0; rr < 16; rr++) {
        int nn = r4*16 + rr;
        xT[((size_t)b*NN + n0 + nn)*CC + c] = tile[c][nn];
    }
}

// ---- x0[b][i] = sum_n x[b,i,n] * nw[b,n] ----
__global__ void __launch_bounds__(256) k_x0(const float* __restrict__ x,
                                            const float* __restrict__ nwt,
                                            float* __restrict__ x0) {
    int b = blockIdx.x >> 6;
    int i = blockIdx.x & 63;
    int tid = threadIdx.x;
    const float4* __restrict__ xr = (const float4*)&x[((size_t)b*CC + i)*NN];
    const float4* __restrict__ wr = (const float4*)&nwt[(size_t)b*NN];
    float s = 0.f;
    for (int t = tid; t < NN/4; t += 256) {
        float4 xv = xr[t];
        float4 wv = wr[t];
        s += xv.x*wv.x + xv.y*wv.y + xv.z*wv.z + xv.w*wv.w;
    }
    __shared__ float red[256];
    red[tid] = s;
    __syncthreads();
    for (int off = 128; off > 0; off >>= 1) {
        if (tid < off) red[tid] += red[tid+off];
        __syncthreads();
    }
    if (tid == 0) x0[b*CC + i] = red[0];
}

// ---- spectral forward partials: A_c/A_s[b][i][k] over n-chunks ----
__global__ void __launch_bounds__(256) k_a(const float* __restrict__ xT,
                                           const float* __restrict__ nodes,
                                           const float* __restrict__ nwt,
                                           const float* __restrict__ modes,
                                           float* __restrict__ pc, float* __restrict__ ps) {
    int bc = blockIdx.x;
    int b = bc / PP, chunk = bc % PP;
    int tid = threadIdx.x;
    int lane = tid & 63;
    int w = tid >> 6;
    int khalf = w & 1;
    int ig = blockIdx.y*2 + (w >> 1);
    int k = khalf*64 + lane;
    int i0 = __builtin_amdgcn_readfirstlane(ig * 16);
    float m0 = modes[k*3+0], m1 = modes[k*3+1], m2 = modes[k*3+2];
    float ac[16], as[16];
#pragma unroll
    for (int j = 0; j < 16; j++) { ac[j]=0.f; as[j]=0.f; }
    int nbase = chunk*LL;
    for (int t = 0; t < LL; t++) {
        int n = nbase + t;
        float nd0 = nodes[(b*NN+n)*3+0], nd1 = nodes[(b*NN+n)*3+1], nd2 = nodes[(b*NN+n)*3+2];
        float nw = nwt[b*NN+n];
        float tt = nd0*m0 + nd1*m1 + nd2*m2;
        float cv = __cosf(tt) * nw, sv = __sinf(tt) * nw;
        const float4* __restrict__ xr4 = (const float4*)&xT[((size_t)b*NN+n)*CC + i0];
        float xv[16];
        *(float4*)&xv[0]  = xr4[0];
        *(float4*)&xv[4]  = xr4[1];
        *(float4*)&xv[8]  = xr4[2];
        *(float4*)&xv[12] = xr4[3];
#pragma unroll
        for (int j = 0; j < 16; j++) {
            ac[j] = fmaf(xv[j], cv, ac[j]);
            as[j] = fmaf(xv[j], sv, as[j]);
        }
    }
    int base = (b*PP + chunk)*CC;
#pragma unroll
    for (int j = 0; j < 16; j++) {
        pc[(size_t)(base + i0 + j)*KK + k] = ac[j];
        ps[(size_t)(base + i0 + j)*KK + k] = as[j];
    }
}

__global__ void k_ared(const float* __restrict__ pc, const float* __restrict__ ps,
                       float* __restrict__ Ac, float* __restrict__ As) {
    int idx = blockIdx.x*256 + threadIdx.x;
    if (idx >= BB*CC*KK) return;
    int b = idx / (CC*KK);
    int r = idx % (CC*KK);
    float sc = 0.f, ss = 0.f;
    for (int ch = 0; ch < PP; ch++) {
        size_t o = ((size_t)(b*PP + ch)*CC)*KK + r;
        sc += pc[o]; ss += ps[o];
    }
    Ac[idx] = sc; As[idx] = ss;
}

// ---- channel mix -> 2*f_c, 2*f_s in [b][k][o] layout, + f0 ----
// 512 threads: (k = tid&127, ig = tid>>7) -> 4-way i-split + LDS reduce
__global__ void __launch_bounds__(512) k_b(const float* __restrict__ Ac, const float* __restrict__ As_,
                                           const float* __restrict__ wc, const float* __restrict__ wsw,
                                           const float* __restrict__ w0, const float* __restrict__ x0,
                                           float* __restrict__ fTc, float* __restrict__ fTs,
                                           float* __restrict__ f0) {
    int b = blockIdx.x / CC, o = blockIdx.x % CC;
    int tid = threadIdx.x;
    int k = tid & 127, ig = tid >> 7;
    float fc = 0.f, fs = 0.f;
    for (int ii = 0; ii < 16; ii++) {
        int i = ig*16 + ii;
        float a_c = Ac[(b*CC+i)*KK + k];
        float a_s = As_[(b*CC+i)*KK + k];
        float wcc = wc[((size_t)(i*CC+o))*KK + k];
        float wss = wsw[((size_t)(i*CC+o))*KK + k];
        fc += a_c*wcc + a_s*wss;
        fs += a_c*wss - a_s*wcc;
    }
    __shared__ float rc[512], rs[512];
    __shared__ float f0s[64];
    rc[tid] = fc; rs[tid] = fs;
    if (tid < 64) f0s[tid] = x0[b*CC + tid] * w0[tid*CC + o];
    __syncthreads();
    if (ig == 0) {
        fc = rc[k] + rc[128+k] + rc[256+k] + rc[384+k];
        fs = rs[k] + rs[128+k] + rs[256+k] + rs[384+k];
        fTc[(b*KK+k)*CC + o] = 2.f*fc;
        fTs[(b*KK+k)*CC + o] = 2.f*fs;
    }
    if (tid == 0) {
        float acc = 0.f;
        for (int i = 0; i < 64; i++) acc += f0s[i];
        f0[b*CC+o] = acc;
    }
}

// ---- build A-panel [b][576][64]; rows 0..255 interleaved {2fc[k], -2fs[k]} ----
__global__ void k_apan(const float* __restrict__ fTc, const float* __restrict__ fTs,
                       const float* __restrict__ WT, const float* __restrict__ w2T,
                       const float* __restrict__ gwT, float* __restrict__ Apan) {
    int idx = blockIdx.x*256 + threadIdx.x;
    if (idx >= BB*KTOT*CC) return;
    int b = idx / (KTOT*CC);
    int r = idx % (KTOT*CC);
    int k = r >> 6, o = r & 63;
    float v;
    if (k < 256) {
        int kp = k >> 1;
        v = (k & 1) ? -fTs[(b*KK + kp)*CC + o] : fTc[(b*KK + kp)*CC + o];
    }
    else if (k < 320) v = WT[(k-256)*CC + o];
    else if (k < 384) v = w2T[(k-320)*CC + o];
    else              v = gwT[(k-384)*CC + o];
    Apan[idx] = v;
}

// ---- edge binning ----
__global__ void k_count(const int* __restrict__ edges, int* __restrict__ counts) {
    int idx = blockIdx.x*256 + threadIdx.x;
    if (idx >= BB*EE) return;
    int tgt = edges[(size_t)idx*2 + 0];
    int b = idx / EE;
    atomicAdd(&counts[b*NN + tgt], 1);
}

__global__ void __launch_bounds__(1024) k_scan(const int* __restrict__ counts,
                                               int* __restrict__ offsets, int* __restrict__ cursor) {
    __shared__ int part[1024];
    int b = blockIdx.x;
    int tid = threadIdx.x;
    int base = tid*16;
    int loc[16]; int s = 0;
    for (int j = 0; j < 16; j++) { loc[j] = counts[b*NN + base + j]; s += loc[j]; }
    part[tid] = s;
    __syncthreads();
    for (int off = 1; off < 1024; off <<= 1) {
        int v = (tid >= off) ? part[tid-off] : 0;
        __syncthreads();
        part[tid] += v;
        __syncthreads();
    }
    int excl = part[tid] - s;
    for (int j = 0; j < 16; j++) {
        offsets[b*NN+base+j] = excl;
        cursor[b*NN+base+j]  = excl;
        excl += loc[j];
    }
}

// ---- fill bins with packed {src, w0, w1, w2} entries ----
__global__ void k_fill(const int* __restrict__ edges, const float* __restrict__ egw,
                       int* __restrict__ cursor, float4* __restrict__ bin4) {
    int idx = blockIdx.x*256 + threadIdx.x;
    if (idx >= BB*EE) return;
    int b = idx / EE;
    int tgt = edges[(size_t)idx*2+0];
    int src = edges[(size_t)idx*2+1];
    const float* __restrict__ ew = &egw[(size_t)idx*3];
    float w0 = ew[0], w1 = ew[1], w2 = ew[2];
    int pos = atomicAdd(&cursor[b*NN+tgt], 1);
    bin4[(size_t)b*EE + pos] = make_float4(__int_as_float(src), w0, w1, w2);
}

// ---- per-node edge accumulate -> gradfT[b][g][n] ----
#define ECAP 1024
__global__ void __launch_bounds__(256) k_edge(const float* __restrict__ xT,
                                              const int* __restrict__ offsets,
                                              const float4* __restrict__ bin4,
                                              float* __restrict__ gradfT) {
    int blk = blockIdx.x;
    int b = blk / (NN/16);
    int n0 = (blk % (NN/16)) * 16;
    int tid = threadIdx.x;
    int lane = tid & 63;
    int w = tid >> 6;                 // 4 waves, 4 nodes each
    __shared__ float4 ebuf[ECAP];
    __shared__ float gl[16][193];
    __shared__ int soff[17];
    if (tid < 16) soff[tid] = offsets[b*NN + n0 + tid];
    if (tid == 16) soff[16] = (n0 + 16 < NN) ? offsets[b*NN + n0 + 16] : EE;
    __syncthreads();
    int base = soff[0];
    int end  = soff[16];
    const float* __restrict__ xTb = &xT[(size_t)b*NN*CC + lane];

    float a0[4], a1[4], a2[4], s0[4], s1[4], s2[4];
#pragma unroll
    for (int q = 0; q < 4; q++) { a0[q]=a1[q]=a2[q]=0.f; s0[q]=s1[q]=s2[q]=0.f; }

    for (int cs = base; cs < end; cs += ECAP) {
        int ce = min(cs + ECAP, end);
        __syncthreads();
        for (int t = cs + tid; t < ce; t += 256)
            ebuf[t - cs] = bin4[(size_t)b*EE + t];
        __syncthreads();
#pragma unroll
        for (int q = 0; q < 4; q++) {
            int nl = w*4 + q;
            int js = max(soff[nl], cs);
            int je = min(soff[nl+1], ce);
#pragma unroll 4
            for (int j = js; j < je; j++) {
                float4 e = ebuf[j - cs];
                int src = __float_as_int(e.x);
                float xs = xTb[(size_t)src*CC];
                a0[q] = fmaf(xs, e.y, a0[q]);
                a1[q] = fmaf(xs, e.z, a1[q]);
                a2[q] = fmaf(xs, e.w, a2[q]);
                s0[q] += e.y; s1[q] += e.z; s2[q] += e.w;
            }
        }
    }
    __syncthreads();
#pragma unroll
    for (int q = 0; q < 4; q++) {
        int nl = w*4 + q;
        float xtgt = xTb[(size_t)(n0 + nl)*CC];
        gl[nl][lane*3+0] = a0[q] - xtgt*s0[q];
        gl[nl][lane*3+1] = a1[q] - xtgt*s1[q];
        gl[nl][lane*3+2] = a2[q] - xtgt*s2[q];
    }
    __syncthreads();
    for (int t = tid; t < 16*192; t += 256) {
        int g = t >> 4, nl = t & 15;
        gradfT[((size_t)b*192+g)*NN + n0 + nl] = gl[nl][g];
    }
}

// ---- final fused GEMM: out = gelu(Apan^T·B + f0), K=576, tile 64o x 64n ----
// h computed in-block: c==4 accumulates both W·x and wx·x; c==5 stages
// softsign(geo)·xw into Bs from registers.
#define KC 64
__global__ void __launch_bounds__(256) k_gemm(const float* __restrict__ x,
                                              const float* __restrict__ nodes,
                                              const float* __restrict__ modes,
                                              const float* __restrict__ geo,
                                              const float* __restrict__ gradfT,
                                              const float* __restrict__ Apan,
                                              const float* __restrict__ f0,
                                              const float* __restrict__ wxT,
                                              const float* __restrict__ gwxT,
                                              float* __restrict__ out) {
    int blk = blockIdx.x;
    int b  = blk >> 8;
    int n0 = (blk & 255) * 64;
    int tid = threadIdx.x;
    int tx = tid & 15;                 // n / 4
    int ty = tid >> 4;                 // o / 4
    __shared__ float As[KC*64];
    __shared__ float Bs[KC*64];
    __shared__ float Ws[64*64];        // wxT staged once
    __shared__ float ndl[192];
    __shared__ float geo3[192];

    {
        const float4* __restrict__ s4 = (const float4*)wxT;
        float4* d4 = (float4*)Ws;
        for (int s = tid; s < 1024; s += 256) d4[s] = s4[s];
    }
    // BUGFIX r7: independent guards so threads 0..191 fill ALL 192 entries of each
    if (tid < 192) ndl[tid]  = nodes[((size_t)b*NN + n0)*3 + tid];
    if (tid < 192) geo3[tid] = geo[((size_t)b*GG + (tid >> 6))*NN + n0 + (tid & 63)];

    float acc[4][4], xw[4][4];
#pragma unroll
    for (int oo = 0; oo < 4; oo++) {
        float fv = f0[b*CC + ty*4 + oo];
#pragma unroll
        for (int nn = 0; nn < 4; nn++) { acc[oo][nn] = fv; xw[oo][nn] = 0.f; }
    }
    const float* __restrict__ Ab = Apan + (size_t)b*KTOT*CC;

    for (int c = 0; c < KTOT/KC; c++) {
        __syncthreads();
        // A chunk: linear float4 copy
        {
            const float4* __restrict__ src = (const float4*)(Ab + (size_t)c*KC*64);
            float4* dst = (float4*)As;
#pragma unroll
            for (int s = 0; s < 4; s++) dst[tid + s*256] = src[tid + s*256];
        }
        // B chunk
        if (c < 4) {
            // 32 interleaved {cos,sin} pairs; one trig eval per (k,n)
#pragma unroll
            for (int s = 0; s < 8; s++) {
                int e = tid + s*256;        // 0..2047
                int pr = e >> 6, n = e & 63;
                int k = c*32 + pr;
                float t = ndl[n*3+0]*modes[k*3+0] + ndl[n*3+1]*modes[k*3+1]
                        + ndl[n*3+2]*modes[k*3+2];
                Bs[(2*pr)*64 + n]   = __cosf(t);
                Bs[(2*pr+1)*64 + n] = __sinf(t);
            }
        } else if (c == 5) {
            // h tile from xw registers (xw finalized in c==4 compute)
#pragma unroll
            for (int oo = 0; oo < 4; oo++) {
                int i = ty*4 + oo;
                float g0 = gwxT[0*CC+i], g1 = gwxT[1*CC+i], g2 = gwxT[2*CC+i];
#pragma unroll
                for (int nn = 0; nn < 4; nn++) {
                    int n = tx*4 + nn;
                    float t = g0*geo3[n] + g1*geo3[64+n] + g2*geo3[128+n];
                    float ssv = t / (1.f + fabsf(t));
                    Bs[i*64 + n] = ssv * xw[oo][nn];
                }
            }
        } else {
            const float* __restrict__ src = (c == 4)
                ? &x[(size_t)b*CC*NN]
                : &gradfT[((size_t)b*192 + (c-6)*64)*NN];
#pragma unroll
            for (int s = 0; s < 16; s++) {
                int e = tid + s*256;
                int r = e >> 6, n = e & 63;
                Bs[e] = src[(size_t)r*NN + n0 + n];
            }
        }
        __syncthreads();
        if (c == 4) {
#pragma unroll 2
            for (int kk = 0; kk < KC; kk++) {
                float4 a4 = *(const float4*)&As[kk*64 + ty*4];
                float4 w4 = *(const float4*)&Ws[kk*64 + ty*4];
                float4 b4 = *(const float4*)&Bs[kk*64 + tx*4];
                float av[4] = {a4.x, a4.y, a4.z, a4.w};
                float wv[4] = {w4.x, w4.y, w4.z, w4.w};
                float bv[4] = {b4.x, b4.y, b4.z, b4.w};
#pragma unroll
                for (int oo = 0; oo < 4; oo++)
#pragma unroll
                    for (int nn = 0; nn < 4; nn++) {
                        acc[oo][nn] = fmaf(av[oo], bv[nn], acc[oo][nn]);
                        xw[oo][nn]  = fmaf(wv[oo], bv[nn], xw[oo][nn]);
                    }
            }
        } else {
#pragma unroll 4
            for (int kk = 0; kk < KC; kk++) {
                float4 a4 = *(const float4*)&As[kk*64 + ty*4];
                float4 b4 = *(const float4*)&Bs[kk*64 + tx*4];
                float av[4] = {a4.x, a4.y, a4.z, a4.w};
                float bv[4] = {b4.x, b4.y, b4.z, b4.w};
#pragma unroll
                for (int oo = 0; oo < 4; oo++)
#pragma unroll
                    for (int nn = 0; nn < 4; nn++)
                        acc[oo][nn] = fmaf(av[oo], bv[nn], acc[oo][nn]);
            }
        }
    }
    // epilogue: exact GELU + float4 store
#pragma unroll
    for (int oo = 0; oo < 4; oo++) {
        int o = ty*4 + oo;
        float4 r4;
        float* rp = (float*)&r4;
#pragma unroll
        for (int nn = 0; nn < 4; nn++) {
            float v = acc[oo][nn];
            rp[nn] = 0.5f * v * (1.f + erff(v * 0.70710678118654752f));
        }
        *(float4*)&out[((size_t)b*CC + o)*NN + n0 + tx*4] = r4;
    }
}

extern "C" void kernel_launch(void* const* d_in, const int* in_sizes, int n_in,
                              void* d_out, int out_size, void* d_ws, size_t ws_size,
                              hipStream_t stream) {
    const float* x      = (const float*)d_in[0];
    const float* nodes  = (const float*)d_in[1];
    const float* nwt    = (const float*)d_in[2];
    const float* geo    = (const float*)d_in[3];
    const int*   edges  = (const int*)d_in[4];
    const float* egw    = (const float*)d_in[5];
    const float* modes  = (const float*)d_in[6];
    const float* wc     = (const float*)d_in[7];
    const float* wsw    = (const float*)d_in[8];
    const float* w0     = (const float*)d_in[9];
    const float* W      = (const float*)d_in[10];
    const float* gw     = (const float*)d_in[11];
    const float* geo_wx = (const float*)d_in[12];
    const float* wx     = (const float*)d_in[13];
    const float* w2     = (const float*)d_in[14];

    float* ws   = (float*)d_ws;
    float* xT   = ws + OFF_XT;
    float* pc   = ws + OFF_PC;
    float* ps   = ws + OFF_PS;
    float* Ac   = ws + OFF_AC;
    float* As   = ws + OFF_AS;
    float* fTc  = ws + OFF_FTC;
    float* fTs  = ws + OFF_FTS;
    float* f0   = ws + OFF_F0;
    float* x0   = ws + OFF_X0;
    int*  counts = (int*)(ws + OFF_CNT);
    int*  offs   = (int*)(ws + OFF_OFFS);
    int*  cur    = (int*)(ws + OFF_CUR);
    float4* bin4 = (float4*)(ws + OFF_BIN4);
    float* gradfT = ws + OFF_GRT;
    float* Apan   = ws + OFF_APAN;
    float* WT   = ws + OFF_WT;
    float* wxT  = ws + OFF_WXT;
    float* w2T  = ws + OFF_W2T;
    float* gwT  = ws + OFF_GWT;
    float* gwxT = ws + OFF_GWXT;
    float* out  = (float*)d_out;

    hipMemsetAsync(counts, 0, (size_t)(BB*NN)*sizeof(int), stream);

    k_prep <<<48, 256, 0, stream>>>(W, gw, geo_wx, wx, w2, WT, wxT, w2T, gwT, gwxT);
    k_xt   <<<BB*(NN/64), 256, 0, stream>>>(x, xT);
    k_x0   <<<BB*CC, 256, 0, stream>>>(x, nwt, x0);
    k_a    <<<dim3(BB*PP, 2), 256, 0, stream>>>(xT, nodes, nwt, modes, pc, ps);
    k_ared <<<(BB*CC*KK)/256, 256, 0, stream>>>(pc, ps, Ac, As);
    k_b    <<<BB*CC, 512, 0, stream>>>(Ac, As, wc, wsw, w0, x0, fTc, fTs, f0);
    k_apan <<<(BB*KTOT*CC + 255)/256, 256, 0, stream>>>(fTc, fTs, WT, w2T, gwT, Apan);
    k_count<<<(BB*EE)/256, 256, 0, stream>>>(edges, counts);
    k_scan <<<BB, 1024, 0, stream>>>(counts, offs, cur);
    k_fill <<<(BB*EE)/256, 256, 0, stream>>>(edges, egw, cur, bin4);
    k_edge <<<BB*(NN/16), 256, 0, stream>>>(xT, offs, bin4, gradfT);
    k_gemm <<<BB*(NN/64), 256, 0, stream>>>(x, nodes, modes, geo, gradfT, Apan, f0,
                                            wxT, gwxT, out);
}